// Round 2
// baseline (213.835 us; speedup 1.0000x reference)
//
#include <hip/hip_runtime.h>
#include <math.h>

// ---- problem constants ----
#define NPIX 12544            // 64*14*14 pixels
#define CIN  2048
#define NB   64               // batch
#define PPIX 196              // pixels per batch image
#define PSPLIT 7              // pixel-splits in gap_partial
#define PCHUNK 28             // 196/7 pixels per split

typedef short  bf16x8 __attribute__((ext_vector_type(8)));
typedef float  f32x4  __attribute__((ext_vector_type(4)));

__device__ inline unsigned short f2bf(float f) {
    // round-to-nearest-even fp32 -> bf16 (inputs are well-behaved, no NaN)
    unsigned int u = __float_as_uint(f);
    u = (u + 0x7fffu + ((u >> 16) & 1u)) >> 16;
    return (unsigned short)u;
}

// ---- kernel 0: transpose+convert W1 [2048][64] f32 -> W1t [64][2048] bf16 ----
__global__ __launch_bounds__(256) void conv_w1(
    const float* __restrict__ W1, unsigned short* __restrict__ W1t)
{
    const int id = blockIdx.x * 256 + threadIdx.x;   // 0..131071
    const int n = id >> 11;                          // out channel 0..63
    const int k = id & 2047;                         // k 0..2047
    W1t[id] = f2bf(W1[k * 64 + n]);                  // write coalesced
}

// ---- kernel 1: a_p = sigmoid(MLP(x_p)) via bf16 MFMA layer-1 GEMM ----
// 512 threads = 8 waves per block, 16 pixels per block, 784 blocks.
// K-split: wave w handles channels [w*256, w*256+256) -> 6272 waves total
// (6.1 waves/SIMD vs 0.77 before). Partials reduced via LDS, then the
// 64->16->8->1 tail runs 16-threads-per-pixel (parallel, not serial).
__global__ __launch_bounds__(512) void attn_scores_mfma(
    const float* __restrict__ x, const unsigned short* __restrict__ W1t,
    const float* __restrict__ b1,
    const float* __restrict__ W2, const float* __restrict__ b2,
    const float* __restrict__ W3, const float* __restrict__ b3,
    const float* __restrict__ W4, const float* __restrict__ b4,
    float* __restrict__ a_out)
{
    __shared__ float part[8][16][68];    // per-wave K-partials (+4 pad)
    __shared__ float h1s[16][68];        // h1 after reduce+bias+relu
    __shared__ float h2s[16][16];
    __shared__ float h3s[16][8];

    const int t    = threadIdx.x;        // 0..511
    const int wv   = t >> 6;             // wave 0..7 -> K-slice
    const int lane = t & 63;
    const int l15  = lane & 15;          // A-row (pixel) / B-col (channel)
    const int q    = lane >> 4;          // k-quad 0..3
    const size_t pix0 = (size_t)blockIdx.x * 16;

    // A: lane reads x[pix0+l15][wv*256 + k0 + q*8 .. +8) as 2x float4
    const float* xr = x + (pix0 + l15) * (size_t)CIN + wv * 256 + q * 8;
    // B: lane reads W1t[ct*16+l15][wv*256 + k0 + q*8 .. +8) (bf16, 16B)
    const unsigned short* wr = W1t + (size_t)l15 * CIN + wv * 256 + q * 8;

    f32x4 acc[4] = {{0,0,0,0},{0,0,0,0},{0,0,0,0},{0,0,0,0}};

#pragma unroll 2
    for (int k0 = 0; k0 < 256; k0 += 32) {
        float4 xa = *(const float4*)(xr + k0);
        float4 xb = *(const float4*)(xr + k0 + 4);
        bf16x8 af;
        af[0] = (short)f2bf(xa.x); af[1] = (short)f2bf(xa.y);
        af[2] = (short)f2bf(xa.z); af[3] = (short)f2bf(xa.w);
        af[4] = (short)f2bf(xb.x); af[5] = (short)f2bf(xb.y);
        af[6] = (short)f2bf(xb.z); af[7] = (short)f2bf(xb.w);
#pragma unroll
        for (int ct = 0; ct < 4; ++ct) {
            bf16x8 bfr = *(const bf16x8*)(wr + (size_t)ct * 16 * CIN + k0);
            acc[ct] = __builtin_amdgcn_mfma_f32_16x16x32_bf16(af, bfr, acc[ct], 0, 0, 0);
        }
    }

    // C/D layout: col = lane&15 (channel-in-tile), row = q*4 + reg (pixel)
#pragma unroll
    for (int ct = 0; ct < 4; ++ct)
#pragma unroll
        for (int r = 0; r < 4; ++r)
            part[wv][q * 4 + r][ct * 16 + l15] = acc[ct][r];
    __syncthreads();

    const int p = t >> 4;                // pixel 0..15 (for t<256)
    const int j = t & 15;                // within-pixel worker 0..15

    // reduce 8 K-partials -> h1 (+bias, relu). 256 threads, float4 each.
    if (t < 256) {
        const int c0 = j * 4;
        f32x4 s = {0, 0, 0, 0};
#pragma unroll
        for (int w = 0; w < 8; ++w) s += *(const f32x4*)&part[w][p][c0];
        const f32x4 bb = *(const f32x4*)(b1 + c0);
        f32x4 hv;
#pragma unroll
        for (int i = 0; i < 4; ++i) hv[i] = fmaxf(s[i] + bb[i], 0.f);
        *(f32x4*)&h1s[p][c0] = hv;
    }
    __syncthreads();

    // layer 2: 16 threads/pixel, thread j computes h2[p][j] (64 FMA)
    if (t < 256) {
        float s = b2[j];
#pragma unroll
        for (int k = 0; k < 64; ++k) s = fmaf(h1s[p][k], W2[k * 16 + j], s);
        h2s[p][j] = fmaxf(s, 0.f);
    }
    __syncthreads();

    // layer 3: 8 threads/pixel
    if (t < 256 && j < 8) {
        float s = b3[j];
#pragma unroll
        for (int k = 0; k < 16; ++k) s = fmaf(h2s[p][k], W3[k * 8 + j], s);
        h3s[p][j] = fmaxf(s, 0.f);
    }
    __syncthreads();

    // layer 4 + sigmoid: 1 thread/pixel
    if (t < 256 && j == 0) {
        float z = b4[0];
#pragma unroll
        for (int k = 0; k < 8; ++k) z = fmaf(h3s[p][k], W4[k], z);
        a_out[pix0 + p] = 1.f / (1.f + expf(-z));
    }
}

// ---- kernel 2: partial weighted sums. grid (2 c-half, 64 b, 7 p-split) ----
// thread owns 4 channels (float4); 2 interleaved accumulators break the
// dependent-FMA chain; 896 blocks = 3584 waves (3.5/SIMD).
__global__ __launch_bounds__(256) void gap_partial(
    const float* __restrict__ x, const float* __restrict__ a,
    float* __restrict__ part)
{
    const int b  = blockIdx.y;
    const int pz = blockIdx.z;                       // 0..6 (28 pixels each)
    const int c0 = (blockIdx.x * 256 + threadIdx.x) * 4;
    const float* xb = x + ((size_t)b * PPIX + pz * PCHUNK) * CIN + c0;
    const float* ab = a + b * PPIX + pz * PCHUNK;

    float4 s0 = {0,0,0,0}, s1 = {0,0,0,0};
#pragma unroll 4
    for (int p = 0; p < PCHUNK; p += 2) {
        const float a0 = ab[p], a1 = ab[p + 1];
        const float4 v0 = *(const float4*)(xb + (size_t)p * CIN);
        const float4 v1 = *(const float4*)(xb + (size_t)(p + 1) * CIN);
        s0.x = fmaf(a0, v0.x, s0.x); s0.y = fmaf(a0, v0.y, s0.y);
        s0.z = fmaf(a0, v0.z, s0.z); s0.w = fmaf(a0, v0.w, s0.w);
        s1.x = fmaf(a1, v1.x, s1.x); s1.y = fmaf(a1, v1.y, s1.y);
        s1.z = fmaf(a1, v1.z, s1.z); s1.w = fmaf(a1, v1.w, s1.w);
    }
    float4 r;
    r.x = s0.x + s1.x; r.y = s0.y + s1.y; r.z = s0.z + s1.z; r.w = s0.w + s1.w;
    *(float4*)(part + ((size_t)pz * NB + b) * CIN + c0) = r;
}

// ---- kernel 3: finalize. grid 64 (one per b), block 512. ----
__global__ __launch_bounds__(512) void gap_final(
    const float* __restrict__ a, const float* __restrict__ part,
    float* __restrict__ out)
{
    __shared__ float red[512];
    const int b = blockIdx.x, t = threadIdx.x;
    red[t] = (t < PPIX) ? a[b * PPIX + t] : 0.f;
    __syncthreads();
#pragma unroll
    for (int s = 256; s > 0; s >>= 1) {
        if (t < s) red[t] += red[t + s];
        __syncthreads();
    }
    const float inv = 1.f / red[0];
    const int c0 = t * 4;
    float4 acc = {0, 0, 0, 0};
#pragma unroll
    for (int z = 0; z < PSPLIT; ++z) {
        const float4 pv = *(const float4*)(part + ((size_t)z * NB + b) * CIN + c0);
        acc.x += pv.x; acc.y += pv.y; acc.z += pv.z; acc.w += pv.w;
    }
    float4 r;
    r.x = acc.x * inv; r.y = acc.y * inv; r.z = acc.z * inv; r.w = acc.w * inv;
    *(float4*)(out + (size_t)b * CIN + c0) = r;
}

extern "C" void kernel_launch(void* const* d_in, const int* in_sizes, int n_in,
                              void* d_out, int out_size, void* d_ws, size_t ws_size,
                              hipStream_t stream)
{
    const float* x  = (const float*)d_in[0];
    const float* W1 = (const float*)d_in[1];
    const float* b1 = (const float*)d_in[2];
    const float* W2 = (const float*)d_in[3];
    const float* b2 = (const float*)d_in[4];
    const float* W3 = (const float*)d_in[5];
    const float* b3 = (const float*)d_in[6];
    const float* W4 = (const float*)d_in[7];
    const float* b4 = (const float*)d_in[8];
    float* out = (float*)d_out;

    // ws layout: W1t bf16 [64][2048] @0 (256KB) | a f32 [12544] @256KB |
    //            part f32 [7][64][2048] @512KB (3.5MB). Total ~4.1 MB.
    unsigned short* W1t = (unsigned short*)d_ws;
    float* a    = (float*)((char*)d_ws + (256 << 10));
    float* part = (float*)((char*)d_ws + (512 << 10));

    conv_w1<<<512, 256, 0, stream>>>(W1, W1t);
    attn_scores_mfma<<<NPIX / 16, 512, 0, stream>>>(x, W1t, b1, W2, b2, W3, b3, W4, b4, a);
    gap_partial<<<dim3(2, NB, PSPLIT), 256, 0, stream>>>(x, a, part);
    gap_final<<<NB, 512, 0, stream>>>(a, part, out);
}

// Round 3
// 209.419 us; speedup vs baseline: 1.0211x; 1.0211x over previous
//
#include <hip/hip_runtime.h>
#include <math.h>

// ---- problem constants ----
#define NPIX 12544            // 64*14*14 pixels
#define CIN  2048
#define NB   64               // batch
#define PPIX 196              // pixels per batch image
#define PSPLIT 14             // pixel-splits in gap_partial
#define PCHUNK 14             // 196/14 pixels per split

typedef short  bf16x8 __attribute__((ext_vector_type(8)));
typedef float  f32x4  __attribute__((ext_vector_type(4)));

__device__ inline unsigned short f2bf(float f) {
    // round-to-nearest-even fp32 -> bf16 (inputs are well-behaved, no NaN)
    unsigned int u = __float_as_uint(f);
    u = (u + 0x7fffu + ((u >> 16) & 1u)) >> 16;
    return (unsigned short)u;
}

// ---- kernel 0: transpose+convert W1 [2048][64] f32 -> W1t [64][2048] bf16 ----
__global__ __launch_bounds__(256) void conv_w1(
    const float* __restrict__ W1, unsigned short* __restrict__ W1t)
{
    const int id = blockIdx.x * 256 + threadIdx.x;   // 0..131071
    const int n = id >> 11;                          // out channel 0..63
    const int k = id & 2047;                         // k 0..2047
    W1t[id] = f2bf(W1[k * 64 + n]);                  // write coalesced
}

// ---- kernel 1: a_p = sigmoid(MLP(x_p)) via bf16 MFMA layer-1 GEMM ----
// 512 threads = 8 waves per block, 16 pixels per block, 784 blocks.
// Wave w handles K in [w*256, w*256+256). Fully-unrolled 8 K-steps with
// x prefetched 4 steps ahead (8 float4 in flight) and W1t double-buffered
// 1 step ahead. All array indices compile-time (no scratch). Partials are
// reduced via LDS; 64->16->8->1 tail runs 16-threads-per-pixel.
__global__ __launch_bounds__(512, 2) void attn_scores_mfma(
    const float* __restrict__ x, const unsigned short* __restrict__ W1t,
    const float* __restrict__ b1,
    const float* __restrict__ W2, const float* __restrict__ b2,
    const float* __restrict__ W3, const float* __restrict__ b3,
    const float* __restrict__ W4, const float* __restrict__ b4,
    float* __restrict__ a_out)
{
    __shared__ float part[8][16][68];    // per-wave K-partials (+4 pad)
    __shared__ float h1s[16][68];        // h1 after reduce+bias+relu
    __shared__ float h2s[16][16];
    __shared__ float h3s[16][8];

    const int t    = threadIdx.x;        // 0..511
    const int wv   = t >> 6;             // wave 0..7 -> K-slice
    const int lane = t & 63;
    const int l15  = lane & 15;          // A-row (pixel) / B-col (channel)
    const int q    = lane >> 4;          // k-quad 0..3
    const size_t pix0 = (size_t)blockIdx.x * 16;

    // A: lane reads x[pix0+l15][wv*256 + 32*i + q*8 .. +8) as 2x float4
    const float* xr = x + (pix0 + l15) * (size_t)CIN + wv * 256 + q * 8;
    // B: lane reads W1t[ct*16+l15][wv*256 + 32*i + q*8 .. +8) (bf16, 16B)
    const unsigned short* wr = W1t + (size_t)l15 * CIN + wv * 256 + q * 8;

    f32x4 acc[4] = {{0,0,0,0},{0,0,0,0},{0,0,0,0},{0,0,0,0}};

    // prefetch x for k-steps 0..3 (8 float4 in flight)
    float4 xv[16];
#pragma unroll
    for (int i = 0; i < 4; ++i) {
        xv[2*i]   = *(const float4*)(xr + 32*i);
        xv[2*i+1] = *(const float4*)(xr + 32*i + 4);
    }
    // prefetch W for k-step 0
    bf16x8 wA[4], wB[4];
#pragma unroll
    for (int ct = 0; ct < 4; ++ct)
        wA[ct] = *(const bf16x8*)(wr + (size_t)ct * 16 * CIN);

#pragma unroll
    for (int i = 0; i < 8; ++i) {
        // issue x loads for step i+4
        if (i < 4) {
            xv[8+2*i] = *(const float4*)(xr + 32*(i+4));
            xv[9+2*i] = *(const float4*)(xr + 32*(i+4) + 4);
        }
        // issue W loads for step i+1 into the other buffer
        if (i < 7) {
            if ((i & 1) == 0) {
#pragma unroll
                for (int ct = 0; ct < 4; ++ct)
                    wB[ct] = *(const bf16x8*)(wr + (size_t)ct * 16 * CIN + 32*(i+1));
            } else {
#pragma unroll
                for (int ct = 0; ct < 4; ++ct)
                    wA[ct] = *(const bf16x8*)(wr + (size_t)ct * 16 * CIN + 32*(i+1));
            }
        }
        // convert this step's x to bf16
        const float4 xa = xv[(2*i) & 15];
        const float4 xb = xv[(2*i+1) & 15];
        bf16x8 af;
        af[0] = (short)f2bf(xa.x); af[1] = (short)f2bf(xa.y);
        af[2] = (short)f2bf(xa.z); af[3] = (short)f2bf(xa.w);
        af[4] = (short)f2bf(xb.x); af[5] = (short)f2bf(xb.y);
        af[6] = (short)f2bf(xb.z); af[7] = (short)f2bf(xb.w);
        if ((i & 1) == 0) {
#pragma unroll
            for (int ct = 0; ct < 4; ++ct)
                acc[ct] = __builtin_amdgcn_mfma_f32_16x16x32_bf16(af, wA[ct], acc[ct], 0, 0, 0);
        } else {
#pragma unroll
            for (int ct = 0; ct < 4; ++ct)
                acc[ct] = __builtin_amdgcn_mfma_f32_16x16x32_bf16(af, wB[ct], acc[ct], 0, 0, 0);
        }
    }

    // C/D layout: col = lane&15 (channel-in-tile), row = q*4 + reg (pixel)
#pragma unroll
    for (int ct = 0; ct < 4; ++ct)
#pragma unroll
        for (int r = 0; r < 4; ++r)
            part[wv][q * 4 + r][ct * 16 + l15] = acc[ct][r];
    __syncthreads();

    const int p = t >> 4;                // pixel 0..15 (for t<256)
    const int j = t & 15;                // within-pixel worker 0..15

    // reduce 8 K-partials -> h1 (+bias, relu). 256 threads, float4 each.
    if (t < 256) {
        const int c0 = j * 4;
        f32x4 s = {0, 0, 0, 0};
#pragma unroll
        for (int w = 0; w < 8; ++w) s += *(const f32x4*)&part[w][p][c0];
        const f32x4 bb = *(const f32x4*)(b1 + c0);
        f32x4 hv;
#pragma unroll
        for (int i = 0; i < 4; ++i) hv[i] = fmaxf(s[i] + bb[i], 0.f);
        *(f32x4*)&h1s[p][c0] = hv;
    }
    __syncthreads();

    // layer 2: 16 threads/pixel, thread j computes h2[p][j] (64 FMA)
    if (t < 256) {
        float s = b2[j];
#pragma unroll
        for (int k = 0; k < 64; ++k) s = fmaf(h1s[p][k], W2[k * 16 + j], s);
        h2s[p][j] = fmaxf(s, 0.f);
    }
    __syncthreads();

    // layer 3: 8 threads/pixel
    if (t < 256 && j < 8) {
        float s = b3[j];
#pragma unroll
        for (int k = 0; k < 16; ++k) s = fmaf(h2s[p][k], W3[k * 8 + j], s);
        h3s[p][j] = fmaxf(s, 0.f);
    }
    __syncthreads();

    // layer 4 + sigmoid: 1 thread/pixel
    if (t < 256 && j == 0) {
        float z = b4[0];
#pragma unroll
        for (int k = 0; k < 8; ++k) z = fmaf(h3s[p][k], W4[k], z);
        a_out[pix0 + p] = 1.f / (1.f + expf(-z));
    }
}

// ---- kernel 2: partial weighted sums. grid (2 c-half, 64 b, 14 p-split) ----
// thread owns 4 channels (float4). All 14 pixel loads issued before any FMA
// (56 VGPR in flight); 1792 blocks = 7168 waves = 28 waves/CU.
__global__ __launch_bounds__(256) void gap_partial(
    const float* __restrict__ x, const float* __restrict__ a,
    float* __restrict__ part)
{
    const int b  = blockIdx.y;
    const int pz = blockIdx.z;                       // 0..13 (14 pixels each)
    const int c0 = (blockIdx.x * 256 + threadIdx.x) * 4;
    const float* xb = x + ((size_t)b * PPIX + pz * PCHUNK) * CIN + c0;
    const float* ab = a + b * PPIX + pz * PCHUNK;

    float av[PCHUNK];
#pragma unroll
    for (int p = 0; p < PCHUNK; ++p) av[p] = ab[p];   // wave-uniform -> scalar

    float4 xv[PCHUNK];
#pragma unroll
    for (int p = 0; p < PCHUNK; ++p)
        xv[p] = *(const float4*)(xb + (size_t)p * CIN);

    float4 s0 = {0,0,0,0}, s1 = {0,0,0,0};
#pragma unroll
    for (int p = 0; p < PCHUNK; p += 2) {
        s0.x = fmaf(av[p], xv[p].x, s0.x);   s0.y = fmaf(av[p], xv[p].y, s0.y);
        s0.z = fmaf(av[p], xv[p].z, s0.z);   s0.w = fmaf(av[p], xv[p].w, s0.w);
        s1.x = fmaf(av[p+1], xv[p+1].x, s1.x); s1.y = fmaf(av[p+1], xv[p+1].y, s1.y);
        s1.z = fmaf(av[p+1], xv[p+1].z, s1.z); s1.w = fmaf(av[p+1], xv[p+1].w, s1.w);
    }
    float4 r;
    r.x = s0.x + s1.x; r.y = s0.y + s1.y; r.z = s0.z + s1.z; r.w = s0.w + s1.w;
    *(float4*)(part + ((size_t)pz * NB + b) * CIN + c0) = r;
}

// ---- kernel 3: finalize. grid 64 (one per b), block 512. ----
__global__ __launch_bounds__(512) void gap_final(
    const float* __restrict__ a, const float* __restrict__ part,
    float* __restrict__ out)
{
    __shared__ float red[512];
    const int b = blockIdx.x, t = threadIdx.x;
    red[t] = (t < PPIX) ? a[b * PPIX + t] : 0.f;
    __syncthreads();
#pragma unroll
    for (int s = 256; s > 0; s >>= 1) {
        if (t < s) red[t] += red[t + s];
        __syncthreads();
    }
    const float inv = 1.f / red[0];
    const int c0 = t * 4;
    float4 acc = {0, 0, 0, 0};
#pragma unroll
    for (int z = 0; z < PSPLIT; ++z) {
        const float4 pv = *(const float4*)(part + ((size_t)z * NB + b) * CIN + c0);
        acc.x += pv.x; acc.y += pv.y; acc.z += pv.z; acc.w += pv.w;
    }
    float4 r;
    r.x = acc.x * inv; r.y = acc.y * inv; r.z = acc.z * inv; r.w = acc.w * inv;
    *(float4*)(out + (size_t)b * CIN + c0) = r;
}

extern "C" void kernel_launch(void* const* d_in, const int* in_sizes, int n_in,
                              void* d_out, int out_size, void* d_ws, size_t ws_size,
                              hipStream_t stream)
{
    const float* x  = (const float*)d_in[0];
    const float* W1 = (const float*)d_in[1];
    const float* b1 = (const float*)d_in[2];
    const float* W2 = (const float*)d_in[3];
    const float* b2 = (const float*)d_in[4];
    const float* W3 = (const float*)d_in[5];
    const float* b3 = (const float*)d_in[6];
    const float* W4 = (const float*)d_in[7];
    const float* b4 = (const float*)d_in[8];
    float* out = (float*)d_out;

    // ws layout: W1t bf16 [64][2048] @0 (256KB) | a f32 [12544] @256KB |
    //            part f32 [14][64][2048] @512KB (7.34MB). Total ~7.9 MB.
    unsigned short* W1t = (unsigned short*)d_ws;
    float* a    = (float*)((char*)d_ws + (256 << 10));
    float* part = (float*)((char*)d_ws + (512 << 10));

    conv_w1<<<512, 256, 0, stream>>>(W1, W1t);
    attn_scores_mfma<<<NPIX / 16, 512, 0, stream>>>(x, W1t, b1, W2, b2, W3, b3, W4, b4, a);
    gap_partial<<<dim3(2, NB, PSPLIT), 256, 0, stream>>>(x, a, part);
    gap_final<<<NB, 512, 0, stream>>>(a, part, out);
}